// Round 3
// baseline (336.267 us; speedup 1.0000x reference)
//
#include <hip/hip_runtime.h>

#define Bb 8
#define Nn 8192
#define Hh 256
#define NUP 2048
#define NDOWN (Nn - NUP)
#define MM 5
#define EPB (NDOWN * MM)   // edges per batch = 30720
#define NBIN 2048          // radial bins
#define KP 288             // padded K for the feat GEMM (256 h + sl,score,1,pad)
#define LDA 36             // LDS row stride (bf16) for A/B tiles

typedef short v8s __attribute__((ext_vector_type(8)));
typedef float v4f __attribute__((ext_vector_type(4)));

#define INFKEY 0x7F800000FFFFFFFFull

// fp32 -> bf16 round-to-nearest-even
__device__ __forceinline__ unsigned short bfc(float f) {
    unsigned u = __float_as_uint(f);
    return (unsigned short)((u + 0x7FFFu + ((u >> 16) & 1u)) >> 16);
}

// Find the bin (descending order) where the kth-largest element lands.
template <int NB>
__device__ void find_kth_bin(const int* hist, int kth, int tid,
                             int* wsumA, int* res, int* out_bin, int* out_cntgt) {
    constexpr int PER = NB / 1024;
    int ln = tid & 63, wv = tid >> 6;
    int b0 = NB - 1 - PER * tid;
    int c0 = hist[b0];
    int c1 = (PER == 2) ? hist[b0 - 1] : 0;
    int tot = c0 + c1;
    int x = tot;
    #pragma unroll
    for (int off = 1; off < 64; off <<= 1) {
        int y = __shfl_up(x, off);
        if (ln >= off) x += y;
    }
    if (ln == 63) wsumA[wv] = x;
    __syncthreads();
    int wbase = 0;
    for (int w = 0; w < wv; w++) wbase += wsumA[w];
    int excl = wbase + x - tot;
    if (excl < kth && excl + c0 >= kth) { res[0] = b0; res[1] = excl; }
    else if (PER == 2 && excl + c0 < kth && excl + c0 + c1 >= kth) { res[0] = b0 - 1; res[1] = excl + c0; }
    __syncthreads();
    *out_bin = res[0];
    *out_cntgt = res[1];
}

// Kernel A: exact top-NUP selection via 3-level radix select, fused compaction
// + up_local inverse map + deg zeroing.
__global__ __launch_bounds__(1024) void select_kernel(
        const float* __restrict__ scores, const float* __restrict__ sl,
        int* __restrict__ mask, float4* __restrict__ upc,
        int* __restrict__ up_local, int* __restrict__ deg) {
    int b = blockIdx.x;
    int tid = threadIdx.x;
    int ln = tid & 63, wv = tid >> 6;
    __shared__ int hist[2048];
    __shared__ int wsumA[16], wsumB[16];
    __shared__ int res[2];
    __shared__ int sbase[2];
    const float* s = scores + (size_t)b * Nn;

    deg[b * NUP + tid] = 0;
    deg[b * NUP + 1024 + tid] = 0;

    hist[tid] = 0; hist[tid + 1024] = 0;
    __syncthreads();
    for (int t = tid; t < Nn; t += 1024)
        atomicAdd(&hist[__float_as_uint(s[t]) >> 21], 1);
    __syncthreads();
    int B1, gt1;
    find_kth_bin<2048>(hist, NUP, tid, wsumA, res, &B1, &gt1);
    int slots1 = NUP - gt1;

    hist[tid] = 0; hist[tid + 1024] = 0;
    __syncthreads();
    for (int t = tid; t < Nn; t += 1024) {
        unsigned u = __float_as_uint(s[t]);
        if ((int)(u >> 21) == B1) atomicAdd(&hist[(u >> 10) & 0x7FF], 1);
    }
    __syncthreads();
    int B2, gt2;
    find_kth_bin<2048>(hist, slots1, tid, wsumA, res, &B2, &gt2);
    int slots2 = slots1 - gt2;
    unsigned hi22 = ((unsigned)B1 << 11) | (unsigned)B2;

    hist[tid] = 0; hist[tid + 1024] = 0;
    __syncthreads();
    for (int t = tid; t < Nn; t += 1024) {
        unsigned u = __float_as_uint(s[t]);
        if ((u >> 10) == hi22) atomicAdd(&hist[u & 0x3FF], 1);
    }
    __syncthreads();
    int B3, gt3;
    find_kth_bin<1024>(hist, slots2, tid, wsumA, res, &B3, &gt3);
    int slots_eq = slots2 - gt3;
    unsigned T = (hi22 << 10) | (unsigned)B3;

    if (tid == 0) { sbase[0] = 0; sbase[1] = 0; }
    __syncthreads();
    for (int t0 = 0; t0 < Nn; t0 += 1024) {
        int node = t0 + tid;
        int g = b * Nn + node;
        unsigned u = __float_as_uint(s[node]);
        bool eq = (u == T);
        unsigned long long bal = __ballot(eq);
        unsigned long long lmask = (1ull << ln) - 1ull;
        int pre = __popcll(bal & lmask);
        if (ln == 0) wsumA[wv] = __popcll(bal);
        __syncthreads();
        int eqbase = sbase[0];
        for (int w = 0; w < wv; w++) eqbase += wsumA[w];
        bool up = (u > T) || (eq && (eqbase + pre) < slots_eq);
        unsigned long long bal2 = __ballot(up);
        int pre2 = __popcll(bal2 & lmask);
        if (ln == 0) wsumB[wv] = __popcll(bal2);
        __syncthreads();
        int upbase = sbase[1];
        for (int w = 0; w < wv; w++) upbase += wsumB[w];
        if (up) {
            float4 c;
            c.x = sl[(size_t)g * 3 + 0];
            c.y = sl[(size_t)g * 3 + 1];
            c.z = sl[(size_t)g * 3 + 2];
            c.w = __int_as_float(node);
            upc[b * NUP + upbase + pre2] = c;
            up_local[g] = upbase + pre2;
        }
        mask[g] = up ? 1 : 0;
        __syncthreads();
        if (tid == 0) {
            int se = 0, su = 0;
            for (int w = 0; w < 16; w++) { se += wsumA[w]; su += wsumB[w]; }
            sbase[0] += se; sbase[1] += su;
        }
        __syncthreads();
    }
}

// Block-wide exclusive scan over 2048 bins (1024 threads x 2 bins each).
__device__ __forceinline__ int scan_bins_2048(const int* hist, int* cur,
                                              int tid, int* wsum) {
    int ln = tid & 63, wv = tid >> 6;
    int i0 = 2 * tid;
    int h0 = hist[i0], h1 = hist[i0 + 1];
    int s = h0 + h1;
    int x = s;
    #pragma unroll
    for (int off = 1; off < 64; off <<= 1) {
        int y = __shfl_up(x, off);
        if (ln >= off) x += y;
    }
    if (ln == 63) wsum[wv] = x;
    __syncthreads();
    int base = 0;
    for (int w = 0; w < wv; w++) base += wsum[w];
    int excl = base + x - s;
    cur[i0] = excl; cur[i0 + 1] = excl + h0;
    int tot = 0;
    for (int w = 0; w < 16; w++) tot += wsum[w];
    __syncthreads();
    return tot;
}

// Kernel P: radial prep. Counting-sort ups by |u|^2 into NBIN linear bins
// (-> upr coords + upk keys), and downs by |d|^2 (-> dord). Rank-adjacent
// downs then have similar radius; knn windows the radius-sorted up array.
__global__ __launch_bounds__(1024) void rprep_kernel(
        const float* __restrict__ sl, const int* __restrict__ mask,
        const float4* __restrict__ upc, float4* __restrict__ upr,
        float* __restrict__ upk, float4* __restrict__ gridp,
        float4* __restrict__ dord) {
    int b = blockIdx.x;
    int tid = threadIdx.x;
    int ln = tid & 63, wv = tid >> 6;
    __shared__ int hist[NBIN];
    __shared__ int cur[NBIN];
    __shared__ float redm[16];
    __shared__ int wsum[16];
    __shared__ float sbw[1];

    float4 u0 = upc[b * NUP + tid];
    float4 u1 = upc[b * NUP + 1024 + tid];
    float k0 = u0.x * u0.x + u0.y * u0.y + u0.z * u0.z;
    float k1 = u1.x * u1.x + u1.y * u1.y + u1.z * u1.z;
    float mx = fmaxf(k0, k1);
    #pragma unroll
    for (int off = 32; off; off >>= 1) mx = fmaxf(mx, __shfl_down(mx, off));
    if (ln == 0) redm[wv] = mx;
    hist[tid] = 0; hist[tid + 1024] = 0;
    __syncthreads();
    if (tid == 0) {
        float m = redm[0];
        for (int w = 1; w < 16; w++) m = fmaxf(m, redm[w]);
        float bw = fmaxf(m, 1e-20f) * (1.0f / NBIN) * 1.0000002f;
        sbw[0] = bw;
        gridp[b] = make_float4(bw * 1.0002f, bw, 0.f, 0.f);  // .x: inflated for bounds
    }
    __syncthreads();
    float bw = sbw[0];
    int b0 = min(NBIN - 1, (int)(k0 / bw));
    int b1 = min(NBIN - 1, (int)(k1 / bw));
    atomicAdd(&hist[b0], 1);
    atomicAdd(&hist[b1], 1);
    __syncthreads();
    scan_bins_2048(hist, cur, tid, wsum);
    int s0 = atomicAdd(&cur[b0], 1);
    upr[b * NUP + s0] = u0; upk[b * NUP + s0] = k0;
    int s1 = atomicAdd(&cur[b1], 1);
    upr[b * NUP + s1] = u1; upk[b * NUP + s1] = k1;

    // ---- downs: counting-sort by radial bin
    __syncthreads();
    hist[tid] = 0; hist[tid + 1024] = 0;
    __syncthreads();
    for (int t = tid; t < Nn; t += 1024) {
        int g = b * Nn + t;
        if (!mask[g]) {
            float x = sl[(size_t)g * 3 + 0];
            float y = sl[(size_t)g * 3 + 1];
            float z = sl[(size_t)g * 3 + 2];
            float k = x * x + y * y + z * z;
            atomicAdd(&hist[min(NBIN - 1, (int)(k / bw))], 1);
        }
    }
    __syncthreads();
    scan_bins_2048(hist, cur, tid, wsum);
    for (int t = tid; t < Nn; t += 1024) {
        int g = b * Nn + t;
        if (!mask[g]) {
            float x = sl[(size_t)g * 3 + 0];
            float y = sl[(size_t)g * 3 + 1];
            float z = sl[(size_t)g * 3 + 2];
            float k = x * x + y * y + z * z;
            int slot = atomicAdd(&cur[min(NBIN - 1, (int)(k / bw))], 1);
            float4 e; e.x = x; e.y = y; e.z = z; e.w = __int_as_float(t);
            dord[b * NDOWN + slot] = e;
        }
    }
}

// Kernel C: exact 5-NN via radial window. 512 threads = 64 rank-sorted downs
// x 8 candidate subsets. Contiguous window in the radius-sorted up array,
// expanded in 512-chunks until the reverse-triangle bound
// dist >= | |u| - |d| | exceeds every lane's 5th-best. Exact (u64 d2|idx
// keys; bin-width + epsilon margins on the bound). Uniform work, no cells,
// no pager, ~6 barriers/block.
__global__ __launch_bounds__(512) void knn_radial(
        const float4* __restrict__ upr, const float* __restrict__ upk,
        const float4* __restrict__ gridp, const float4* __restrict__ dord,
        const int* __restrict__ up_local, int* __restrict__ knn,
        int* __restrict__ deg) {
    int b = blockIdx.y;
    int tid = threadIdx.x;
    int sub = tid >> 6, dn = tid & 63;   // 8 subs x 64 downs
    __shared__ float4 stage[512];
    __shared__ unsigned long long part[40 * 64];  // [(sub*5+m)*64 + dn]
    __shared__ int sflags[2];

    float binw = gridp[b].x;
    float4 d = dord[b * NDOWN + blockIdx.x * 64 + dn];
    float xd = d.x, yd = d.y, zd = d.z;
    int node = __float_as_int(d.w);
    float rd = sqrtf(xd * xd + yd * yd + zd * zd);

    unsigned long long bd[MM];
    #pragma unroll
    for (int m = 0; m < MM; m++) bd[m] = INFKEY;

    auto ins = [&](unsigned long long* L, unsigned long long cand) {
        #pragma unroll
        for (int m = 0; m < MM; m++) {
            bool lt = cand < L[m];
            unsigned long long lo = lt ? cand : L[m];
            unsigned long long hi = lt ? L[m] : cand;
            L[m] = lo; cand = hi;
        }
    };

    const float4* U = upr + b * NUP;
    const float* K = upk + b * NUP;

    auto scanChunk = [&](int base, int cnt) {
        __syncthreads();   // previous stage fully consumed
        if (tid < cnt) stage[tid] = U[base + tid];
        __syncthreads();
        unsigned thr_ = (unsigned)(bd[MM - 1] >> 32);
        int n0 = (cnt * sub) >> 3, n1 = (cnt * (sub + 1)) >> 3;
        for (int j = n0; j < n1; ++j) {
            float4 c = stage[j];
            float dx = c.x - xd, dy = c.y - yd, dz = c.z - zd;
            float d2 = fmaf(dx, dx, fmaf(dy, dy, dz * dz));
            unsigned du = __float_as_uint(d2);
            if (du <= thr_) {
                unsigned long long key = ((unsigned long long)du << 32) |
                                         (unsigned long long)(unsigned)__float_as_int(c.w);
                if (key < bd[MM - 1]) {
                    ins(bd, key);
                    thr_ = (unsigned)(bd[MM - 1] >> 32);
                }
            }
        }
    };

    int pos0 = ((blockIdx.x * 64 + 32) * NUP) / NDOWN;   // rank-proportional
    int lo = min(max(pos0 - 256, 0), NUP - 512);
    int hi = lo + 512;
    scanChunk(lo, 512);

    while (true) {
        float T2 = __uint_as_float((unsigned)(bd[MM - 1] >> 32)); // +inf if <5 found
        bool needL = false, needR = false;
        if (lo > 0) {
            float kL = K[lo - 1] + binw;           // upper bound |u|^2 left-out
            float ub = sqrtf(fmaxf(kL, 0.f));
            float gap = rd - ub;
            needL = !(gap > 0.f && gap * gap * 0.999f > T2 + 1e-7f);
        }
        if (hi < NUP) {
            float kR = K[hi] - binw;               // lower bound |u|^2 right-out
            float lb = sqrtf(fmaxf(kR, 0.f));
            float gap = lb - rd;
            needR = !(gap > 0.f && gap * gap * 0.999f > T2 + 1e-7f);
        }
        __syncthreads();
        if (tid == 0) { sflags[0] = 0; sflags[1] = 0; }
        __syncthreads();
        unsigned long long bL = __ballot(needL);
        unsigned long long bR = __ballot(needR);
        if ((tid & 63) == 0) {
            if (bL) sflags[0] = 1;
            if (bR) sflags[1] = 1;
        }
        __syncthreads();
        int nL = sflags[0] && (lo > 0);
        int nR = sflags[1] && (hi < NUP);
        if (!nL && !nR) break;
        if (nL) { int c = min(512, lo); scanChunk(lo - c, c); lo -= c; }
        if (nR) { int c = min(512, NUP - hi); scanChunk(hi, c); hi += c; }
    }

    // final merge + outputs
    __syncthreads();
    #pragma unroll
    for (int m = 0; m < MM; m++) part[(sub * MM + m) * 64 + dn] = bd[m];
    __syncthreads();
    if (sub == 0) {
        unsigned long long fin[MM];
        #pragma unroll
        for (int m = 0; m < MM; m++) fin[m] = 0xFFFFFFFFFFFFFFFFull;
        #pragma unroll
        for (int l = 0; l < 8; l++)
            #pragma unroll
            for (int m = 0; m < MM; m++) ins(fin, part[(l * MM + m) * 64 + dn]);
        int g = b * Nn + node;
        #pragma unroll
        for (int m = 0; m < MM; m++) {
            int nid = (int)(unsigned)(fin[m] & 0xFFFFFFFFull);
            knn[g * MM + m] = nid;
            atomicAdd(&deg[b * NUP + up_local[b * Nn + nid]], 1);
        }
    }
}

// Kernel W: Wt[n][k] = bf16 of W-ext^T.
__global__ void wt_kernel(const float* __restrict__ W, const float* __restrict__ bias,
                          unsigned short* __restrict__ Wt) {
    int n = blockIdx.x;
    int k = threadIdx.x;
    Wt[n * KP + k] = bfc(W[(size_t)k * Hh + n]);
    if (k < KP - 256) {
        int kk = 256 + k;
        unsigned short v = 0;
        if (kk < 260)       v = bfc(W[(size_t)kk * Hh + n]);
        else if (kk == 260) v = bfc(bias[n]);
        Wt[n * KP + kk] = v;
    }
}

// Kernel B: feat GEMM via bf16 MFMA. C[128m x 128n] per block, 4 waves of 64x64.
__global__ void feat_mfma(const float* __restrict__ h, const float* __restrict__ sl,
                          const float* __restrict__ sc, const unsigned short* __restrict__ Wt,
                          float* __restrict__ out) {
    int b = blockIdx.z;
    int m0 = blockIdx.x * 128;
    int n0 = blockIdx.y * 128;
    int tid = threadIdx.x;
    __shared__ unsigned short Al[128 * LDA];
    __shared__ unsigned short Bl[128 * LDA];
    int wid = tid >> 6, lane = tid & 63;
    int wm = (wid & 1) * 64, wn = (wid >> 1) * 64;
    int lm = lane & 15, quad = lane >> 4;
    v4f acc[4][4];
    #pragma unroll
    for (int i = 0; i < 4; i++)
        #pragma unroll
        for (int j = 0; j < 4; j++)
            acc[i][j] = (v4f){0.f, 0.f, 0.f, 0.f};
    const float* Ab = h + ((size_t)b * Nn + m0) * Hh;
    for (int t = 0; t < 9; t++) {
        int k0 = t * 32;
        __syncthreads();
        if (t < 8) {
            #pragma unroll
            for (int q = 0; q < 4; q++) {
                int e = q * 256 + tid;
                int row = e >> 3, kq = e & 7;
                float4 v = *(const float4*)(Ab + (size_t)row * Hh + k0 + kq * 4);
                ushort4 o = make_ushort4(bfc(v.x), bfc(v.y), bfc(v.z), bfc(v.w));
                *(ushort4*)(Al + row * LDA + kq * 4) = o;
            }
        } else if (tid < 128) {
            int row = tid;
            int g = b * Nn + m0 + row;
            unsigned short r[32];
            #pragma unroll
            for (int k = 0; k < 32; k++) r[k] = 0;
            r[0] = bfc(sl[(size_t)g * 3 + 0]);
            r[1] = bfc(sl[(size_t)g * 3 + 1]);
            r[2] = bfc(sl[(size_t)g * 3 + 2]);
            r[3] = bfc(sc[g]);
            r[4] = 0x3F80;  // 1.0 (bias column)
            #pragma unroll
            for (int q = 0; q < 8; q++)
                *(ushort4*)(Al + row * LDA + q * 4) =
                    make_ushort4(r[q * 4], r[q * 4 + 1], r[q * 4 + 2], r[q * 4 + 3]);
        }
        #pragma unroll
        for (int q = 0; q < 4; q++) {
            int e = q * 256 + tid;
            int n = e >> 3, kq = e & 7;
            ushort4 v = *(const ushort4*)(Wt + (size_t)(n0 + n) * KP + k0 + kq * 4);
            *(ushort4*)(Bl + n * LDA + kq * 4) = v;
        }
        __syncthreads();
        v8s af[4], bfr[4];
        #pragma unroll
        for (int i = 0; i < 4; i++)
            af[i] = *(const v8s*)(Al + (wm + i * 16 + lm) * LDA + quad * 8);
        #pragma unroll
        for (int j = 0; j < 4; j++)
            bfr[j] = *(const v8s*)(Bl + (wn + j * 16 + lm) * LDA + quad * 8);
        #pragma unroll
        for (int i = 0; i < 4; i++)
            #pragma unroll
            for (int j = 0; j < 4; j++)
                acc[i][j] = __builtin_amdgcn_mfma_f32_16x16x32_bf16(af[i], bfr[j], acc[i][j], 0, 0, 0);
    }
    #pragma unroll
    for (int i = 0; i < 4; i++) {
        #pragma unroll
        for (int r = 0; r < 4; r++) {
            int row = m0 + wm + i * 16 + quad * 4 + r;
            size_t base = ((size_t)b * Nn + row) * Hh + n0 + wn + lm;
            #pragma unroll
            for (int j = 0; j < 4; j++)
                out[base + j * 16] = acc[i][j][r];
        }
    }
}

// CSR build: per-batch exclusive scan of deg -> rowptr (+ cursor copy).
__global__ __launch_bounds__(1024) void csr_scan(const int* __restrict__ deg,
                                                 int* __restrict__ rowptr,
                                                 int* __restrict__ cursor) {
    int b = blockIdx.x;
    int tid = threadIdx.x;
    int ln = tid & 63, wv = tid >> 6;
    __shared__ int wsum[16];
    int d0 = deg[b * NUP + 2 * tid], d1 = deg[b * NUP + 2 * tid + 1];
    int s = d0 + d1;
    int x = s;
    #pragma unroll
    for (int off = 1; off < 64; off <<= 1) {
        int y = __shfl_up(x, off);
        if (ln >= off) x += y;
    }
    if (ln == 63) wsum[wv] = x;
    __syncthreads();
    int base = 0;
    for (int w = 0; w < wv; w++) base += wsum[w];
    int excl = base + x - s;
    rowptr[b * (NUP + 1) + 2 * tid] = excl;
    rowptr[b * (NUP + 1) + 2 * tid + 1] = excl + d0;
    cursor[b * NUP + 2 * tid] = excl;
    cursor[b * NUP + 2 * tid + 1] = excl + d0;
    if (tid == 1023) rowptr[b * (NUP + 1) + NUP] = excl + s;
}

// CSR build: fill edge array (src = batch-local down node id).
__global__ void csr_fill(const int* __restrict__ mask, const int* __restrict__ knn,
                         const int* __restrict__ up_local, int* __restrict__ cursor,
                         int* __restrict__ edges) {
    int b = blockIdx.y;
    int i = blockIdx.x * 256 + threadIdx.x;
    int g = b * Nn + i;
    if (mask[g]) return;
    #pragma unroll
    for (int m = 0; m < MM; m++) {
        int un = knn[g * MM + m];
        int slot = atomicAdd(&cursor[b * NUP + up_local[b * Nn + un]], 1);
        edges[b * EPB + slot] = i;
    }
}

// Kernel D: gather-max. One wave per up node; lanes own 4 cols (float4).
__global__ void gather_kernel(const float4* __restrict__ upc, const int* __restrict__ rowptr,
                              const int* __restrict__ edges, float* __restrict__ out) {
    int b = blockIdx.y;
    int u = blockIdx.x * 4 + (threadIdx.x >> 6);
    int lane = threadIdx.x & 63;
    int node = __float_as_int(upc[b * NUP + u].w);
    int start = rowptr[b * (NUP + 1) + u];
    int end   = rowptr[b * (NUP + 1) + u + 1];
    const int* eb = edges + b * EPB;
    size_t rowbase = (size_t)b * Nn * Hh + (size_t)(lane << 2);
    float4 a0 = make_float4(-3.4e38f, -3.4e38f, -3.4e38f, -3.4e38f);
    float4 a1 = a0;
    int e = start;
    for (; e + 2 <= end; e += 2) {
        int s0 = eb[e], s1 = eb[e + 1];
        float4 v0 = *(const float4*)(out + rowbase + (size_t)s0 * Hh);
        float4 v1 = *(const float4*)(out + rowbase + (size_t)s1 * Hh);
        a0.x = fmaxf(a0.x, v0.x); a0.y = fmaxf(a0.y, v0.y);
        a0.z = fmaxf(a0.z, v0.z); a0.w = fmaxf(a0.w, v0.w);
        a1.x = fmaxf(a1.x, v1.x); a1.y = fmaxf(a1.y, v1.y);
        a1.z = fmaxf(a1.z, v1.z); a1.w = fmaxf(a1.w, v1.w);
    }
    if (e < end) {
        int s0 = eb[e];
        float4 v0 = *(const float4*)(out + rowbase + (size_t)s0 * Hh);
        a0.x = fmaxf(a0.x, v0.x); a0.y = fmaxf(a0.y, v0.y);
        a0.z = fmaxf(a0.z, v0.z); a0.w = fmaxf(a0.w, v0.w);
    }
    float4 r;
    r.x = fmaxf(a0.x, a1.x); r.y = fmaxf(a0.y, a1.y);
    r.z = fmaxf(a0.z, a1.z); r.w = fmaxf(a0.w, a1.w);
    if (start == end) r = make_float4(0.f, 0.f, 0.f, 0.f);
    *(float4*)(out + rowbase + (size_t)node * Hh) = r;
}

// Kernel E: zero down rows, write mask tail.
__global__ void finalize_kernel(const int* __restrict__ mask, float* __restrict__ out) {
    int b = blockIdx.y;
    int node = blockIdx.x * 4 + (threadIdx.x >> 6);
    int g = b * Nn + node;
    int lane = threadIdx.x & 63;
    bool up = mask[g] != 0;
    if (!up)
        *(float4*)(out + (size_t)g * Hh + (lane << 2)) = make_float4(0.f, 0.f, 0.f, 0.f);
    if (lane == 0) out[(size_t)Bb * Nn * Hh + g] = up ? 1.0f : 0.0f;
}

extern "C" void kernel_launch(void* const* d_in, const int* in_sizes, int n_in,
                              void* d_out, int out_size, void* d_ws, size_t ws_size,
                              hipStream_t stream) {
    const float* h    = (const float*)d_in[0];
    const float* sl   = (const float*)d_in[1];
    const float* sc   = (const float*)d_in[2];
    const float* W    = (const float*)d_in[3];
    const float* bias = (const float*)d_in[4];

    char* ws = (char*)d_ws;
    int* mask = (int*)ws;                 ws += (size_t)Bb * Nn * sizeof(int);
    int* knn  = (int*)ws;                 ws += (size_t)Bb * Nn * MM * sizeof(int);
    float4* upc = (float4*)ws;            ws += (size_t)Bb * NUP * sizeof(float4);
    unsigned short* Wt = (unsigned short*)ws; ws += (size_t)Hh * KP * sizeof(unsigned short);
    int* up_local = (int*)ws;             ws += (size_t)Bb * Nn * sizeof(int);
    int* deg = (int*)ws;                  ws += (size_t)Bb * NUP * sizeof(int);
    int* cursor = (int*)ws;               ws += (size_t)Bb * NUP * sizeof(int);
    int* rowptr = (int*)ws;               ws += (size_t)Bb * (NUP + 1) * sizeof(int);
    int* edges = (int*)ws;                ws += (size_t)Bb * EPB * sizeof(int);
    float4* upr = (float4*)ws;            ws += (size_t)Bb * NUP * sizeof(float4);
    float* upk = (float*)ws;              ws += (size_t)Bb * NUP * sizeof(float);
    float4* gridp = (float4*)ws;          ws += (size_t)Bb * 2 * sizeof(float4);
    float4* dord = (float4*)ws;           // B*NDOWN float4
    float* outf = (float*)d_out;

    dim3 blk(256);
    select_kernel<<<dim3(Bb), dim3(1024), 0, stream>>>(sc, sl, mask, upc, up_local, deg);
    rprep_kernel<<<dim3(Bb), dim3(1024), 0, stream>>>(sl, mask, upc, upr, upk, gridp, dord);
    knn_radial<<<dim3(NDOWN / 64, Bb), dim3(512), 0, stream>>>(upr, upk, gridp, dord,
                                                               up_local, knn, deg);
    csr_scan<<<dim3(Bb), dim3(1024), 0, stream>>>(deg, rowptr, cursor);
    csr_fill<<<dim3(Nn / 256, Bb), blk, 0, stream>>>(mask, knn, up_local, cursor, edges);
    wt_kernel<<<dim3(Hh), blk, 0, stream>>>(W, bias, Wt);
    feat_mfma<<<dim3(Nn / 128, 2, Bb), blk, 0, stream>>>(h, sl, sc, Wt, outf);
    gather_kernel<<<dim3(NUP / 4, Bb), blk, 0, stream>>>(upc, rowptr, edges, outf);
    finalize_kernel<<<dim3(Nn / 4, Bb), blk, 0, stream>>>(mask, outf);
}